// Round 1
// baseline (749.337 us; speedup 1.0000x reference)
//
#include <hip/hip_runtime.h>

// Matcher: B=8, H=W=48, HW=2304.
// out[b,0..1,:] = global branch: max_p init_sim[b,p,j]*init_seg[b,c,p]
// out[b,2..3,:] = local branch: per-row top4 cut/min on scaled prev_sim rows,
//                 column max of (kept value | per-row fill).
#define B_   8
#define HW_  2304
#define NCH  64            // p-chunks for global kernel
#define RPC  (HW_ / NCH)   // 36 rows per chunk
#define NOUT (B_ * 4 * HW_)

// Monotone float<->uint key mapping (total order incl. negatives).
__device__ inline unsigned fkey(float f) {
    unsigned u = __float_as_uint(f);
    return (u & 0x80000000u) ? ~u : (u | 0x80000000u);
}
__device__ inline float funkey(unsigned k) {
    return (k & 0x80000000u) ? __uint_as_float(k & 0x7FFFFFFFu)
                             : __uint_as_float(~k);
}

__global__ __launch_bounds__(256) void k_init(unsigned* __restrict__ out,
                                              unsigned* __restrict__ F) {
    int idx = blockIdx.x * 256 + threadIdx.x;
    if (idx < 16) F[idx] = 0u;                 // fill-max accumulators (nonneg floats as uint)
    if (idx < NOUT) {
        int c = (idx / HW_) & 3;
        out[idx] = (c < 2) ? 0x007FFFFFu       // fkey(-inf) for global channels
                           : 0u;               // 0.0f for local channels
    }
}

// Global branch: grid (NCH, B), 192 threads, 3 float4 column-groups/thread.
__global__ __launch_bounds__(192) void k_global(const float* __restrict__ sim,
                                                const float* __restrict__ seg,
                                                unsigned* __restrict__ out) {
    const int b = blockIdx.y;
    const int t = threadIdx.x;
    const int p0 = blockIdx.x * RPC;
    const float4* simb = (const float4*)(sim + (size_t)b * HW_ * HW_);
    const float* seg0 = seg + (size_t)b * 2 * HW_;
    const float NI = -__builtin_inff();
    float4 m0[3], m1[3];
#pragma unroll
    for (int k = 0; k < 3; ++k) {
        m0[k].x = NI; m0[k].y = NI; m0[k].z = NI; m0[k].w = NI;
        m1[k].x = NI; m1[k].y = NI; m1[k].z = NI; m1[k].w = NI;
    }
    for (int p = p0; p < p0 + RPC; ++p) {
        float s0 = seg0[p];
        float s1 = seg0[HW_ + p];
        const float4* row = simb + (size_t)p * (HW_ / 4);
#pragma unroll
        for (int k = 0; k < 3; ++k) {
            float4 v = row[t + k * 192];
            m0[k].x = fmaxf(m0[k].x, v.x * s0); m1[k].x = fmaxf(m1[k].x, v.x * s1);
            m0[k].y = fmaxf(m0[k].y, v.y * s0); m1[k].y = fmaxf(m1[k].y, v.y * s1);
            m0[k].z = fmaxf(m0[k].z, v.z * s0); m1[k].z = fmaxf(m1[k].z, v.z * s1);
            m0[k].w = fmaxf(m0[k].w, v.w * s0); m1[k].w = fmaxf(m1[k].w, v.w * s1);
        }
    }
    unsigned* o0 = out + (size_t)b * 4 * HW_;
    unsigned* o1 = o0 + HW_;
#pragma unroll
    for (int k = 0; k < 3; ++k) {
        int j = 4 * (t + k * 192);
        atomicMax(o0 + j + 0, fkey(m0[k].x)); atomicMax(o1 + j + 0, fkey(m1[k].x));
        atomicMax(o0 + j + 1, fkey(m0[k].y)); atomicMax(o1 + j + 1, fkey(m1[k].y));
        atomicMax(o0 + j + 2, fkey(m0[k].z)); atomicMax(o1 + j + 2, fkey(m1[k].z));
        atomicMax(o0 + j + 3, fkey(m0[k].w)); atomicMax(o1 + j + 3, fkey(m1[k].w));
    }
}

// Local branch: one block per (b, row i). grid (HW, B), 192 threads.
__global__ __launch_bounds__(192) void k_local(const float* __restrict__ sim,
                                               const float* __restrict__ seg,
                                               unsigned* __restrict__ out,
                                               unsigned* __restrict__ F) {
    const int b = blockIdx.y;
    const int i = blockIdx.x;
    const int t = threadIdx.x;
    const float4* row = (const float4*)(sim + ((size_t)b * HW_ + i) * HW_);
    float x[12];
#pragma unroll
    for (int k = 0; k < 3; ++k) {
        float4 v = row[t + k * 192];
        x[4*k+0] = v.x; x[4*k+1] = v.y; x[4*k+2] = v.z; x[4*k+3] = v.w;
    }
    const float NI = -__builtin_inff();
    float a0 = NI, a1 = NI, a2 = NI, a3 = NI, mn = __builtin_inff();
#pragma unroll
    for (int k = 0; k < 12; ++k) {
        float v = x[k];
        mn = fminf(mn, v);
        if (v > a3) {                           // sorted-desc top4 insert (duplicate-safe)
            if (v > a0)      { a3 = a2; a2 = a1; a1 = a0; a0 = v; }
            else if (v > a1) { a3 = a2; a2 = a1; a1 = v; }
            else if (v > a2) { a3 = a2; a2 = v; }
            else             { a3 = v; }
        }
    }
    // wave64 butterfly: merge sorted-desc 4-lists (k-th of merge formulas)
#pragma unroll
    for (int off = 32; off >= 1; off >>= 1) {
        float b0 = __shfl_down(a0, off);
        float b1 = __shfl_down(a1, off);
        float b2 = __shfl_down(a2, off);
        float b3 = __shfl_down(a3, off);
        float bm = __shfl_down(mn, off);
        mn = fminf(mn, bm);
        float r0 = fmaxf(a0, b0);
        float r1 = fmaxf(fmaxf(a1, b1), fminf(a0, b0));
        float r2 = fmaxf(fmaxf(a2, b2), fmaxf(fminf(a1, b0), fminf(a0, b1)));
        float r3 = fmaxf(fmaxf(a3, b3),
                   fmaxf(fminf(a2, b0), fmaxf(fminf(a1, b1), fminf(a0, b2))));
        a0 = r0; a1 = r1; a2 = r2; a3 = r3;
    }
    __shared__ float s4[3][4];
    __shared__ float smn[3];
    __shared__ float scut, smin;
    int wave = t >> 6;
    if ((t & 63) == 0) {
        s4[wave][0] = a0; s4[wave][1] = a1; s4[wave][2] = a2; s4[wave][3] = a3;
        smn[wave] = mn;
    }
    __syncthreads();
    if (t == 0) {
        float c0 = s4[0][0], c1 = s4[0][1], c2 = s4[0][2], c3 = s4[0][3];
#pragma unroll
        for (int w = 1; w < 3; ++w) {
            float b0 = s4[w][0], b1 = s4[w][1], b2 = s4[w][2], b3 = s4[w][3];
            float r0 = fmaxf(c0, b0);
            float r1 = fmaxf(fmaxf(c1, b1), fminf(c0, b0));
            float r2 = fmaxf(fmaxf(c2, b2), fmaxf(fminf(c1, b0), fminf(c0, b1)));
            float r3 = fmaxf(fmaxf(c3, b3),
                       fmaxf(fminf(c2, b0), fmaxf(fminf(c1, b1), fminf(c0, b2))));
            c0 = r0; c1 = r1; c2 = r2; c3 = r3;
        }
        scut = c3;                              // raw 4th-largest of the row
        smin = fminf(fminf(smn[0], smn[1]), smn[2]);
    }
    __syncthreads();
    const float t4raw = scut;
    const float mnraw = smin;
#pragma unroll
    for (int c = 0; c < 2; ++c) {
        float s   = seg[((size_t)b * 2 + c) * HW_ + i];
        float cut = s * t4raw;                  // == top_k(scaled row)[3] by monotonicity
        float mnv = s * mnraw;                  // == min(scaled row)
        float fill = (mnv > 0.f) ? mnv : 0.f;   // value of every non-kept element (exact)
        if (t == 0) atomicMax(&F[b * 2 + c], __float_as_uint(fill));
        unsigned* oc = out + ((size_t)b * 4 + 2 + c) * HW_;
#pragma unroll
        for (int k = 0; k < 3; ++k) {
            int j = 4 * (t + k * 192);
#pragma unroll
            for (int m = 0; m < 4; ++m) {
                float v = s * x[4 * k + m];
                if (v >= cut) {                 // !(score < cut) -> kept
                    float e = fmaxf(v - mnv, 0.f) + mnv;  // reference's exact fp sequence
                    e = (e > 0.f) ? e : 0.f;    // clamp: F>=0 dominates, keeps uint-max valid
                    atomicMax(oc + j + m, __float_as_uint(e));
                }
            }
        }
    }
}

__global__ __launch_bounds__(256) void k_final(unsigned* __restrict__ out,
                                               const unsigned* __restrict__ F) {
    int idx = blockIdx.x * 256 + threadIdx.x;
    if (idx >= NOUT) return;
    int c = (idx / HW_) & 3;
    if (c < 2) {
        ((float*)out)[idx] = funkey(out[idx]);
    } else {
        int b = idx / (4 * HW_);
        float f = __uint_as_float(F[b * 2 + (c - 2)]);
        ((float*)out)[idx] = fmaxf(__uint_as_float(out[idx]), f);
    }
}

extern "C" void kernel_launch(void* const* d_in, const int* in_sizes, int n_in,
                              void* d_out, int out_size, void* d_ws, size_t ws_size,
                              hipStream_t stream) {
    const float* init_sim = (const float*)d_in[0];
    const float* prev_sim = (const float*)d_in[1];
    const float* init_seg = (const float*)d_in[2];
    const float* prev_seg = (const float*)d_in[3];
    unsigned* out = (unsigned*)d_out;
    unsigned* F   = (unsigned*)d_ws;   // 16 uints: per-(b,channel) fill maxima

    k_init  <<<(NOUT + 255) / 256, 256, 0, stream>>>(out, F);
    k_global<<<dim3(NCH, B_), 192, 0, stream>>>(init_sim, init_seg, out);
    k_local <<<dim3(HW_, B_), 192, 0, stream>>>(prev_sim, prev_seg, out, F);
    k_final <<<(NOUT + 255) / 256, 256, 0, stream>>>(out, F);
}